// Round 1
// baseline (630.386 us; speedup 1.0000x reference)
//
#include <hip/hip_runtime.h>
#include <stdint.h>
#include <stddef.h>

static constexpr int NB = 2;       // batch
static constexpr int SS = 2048;    // seq
static constexpr int DDim = 1024;  // model dim
static constexpr int NH = 16;      // heads
static constexpr size_t BSD = (size_t)NB * SS * DDim;  // 4194304
static constexpr size_t DDn = (size_t)DDim * DDim;     // 1048576

typedef __attribute__((ext_vector_type(4))) float f32x4;
typedef __attribute__((ext_vector_type(8))) short bf16x8;

__device__ __forceinline__ short f2bf(float f) {
  union { float f; unsigned u; } v; v.f = f;
  unsigned r = v.u + 0x7FFFu + ((v.u >> 16) & 1u);
  return (short)(r >> 16);
}

__device__ __forceinline__ void gload_lds16(const void* src, void* dst) {
  __builtin_amdgcn_global_load_lds(
      (const __attribute__((address_space(1))) void*)src,
      (__attribute__((address_space(3))) void*)dst, 16, 0, 0);
}

// ---------------- fp32 -> bf16 convert (8 elems/thread) ----------------
__global__ void cvt_k(const float* __restrict__ in, short* __restrict__ out, int n8) {
  int i = blockIdx.x * 256 + threadIdx.x;
  if (i >= n8) return;
  const f32x4* p = (const f32x4*)in + (size_t)i * 2;
  f32x4 a = p[0], c = p[1];
  bf16x8 o;
  o[0] = f2bf(a[0]); o[1] = f2bf(a[1]); o[2] = f2bf(a[2]); o[3] = f2bf(a[3]);
  o[4] = f2bf(c[0]); o[5] = f2bf(c[1]); o[6] = f2bf(c[2]); o[7] = f2bf(c[3]);
  ((bf16x8*)out)[i] = o;
}

// ---------------- shared 128x128 bf16 C=A*B^T core ----------------
// LDS tiles [128][32] linear (global_load_lds), single-buffer, 2 barriers/K-step.
// MFMA 16x16x32 bf16. 4 waves in 2x2, each 64x64 (acc[4][4]).
__device__ __forceinline__ void gemm_core(
    const short* __restrict__ A, const short* __restrict__ Bm,
    int rowA, int rowB, int ld, int nk,
    short* la, short* lb, int wid, int lane, f32x4 (&acc)[4][4]) {
  const int ar = lane & 15, ak = (lane >> 4) * 8;
  const int srow = lane >> 2, scol = (lane & 3) * 8;
  const int wr = wid >> 1, wc = wid & 1;
  for (int kt = 0; kt < nk; ++kt) {
    const int k0 = kt * 32;
#pragma unroll
    for (int c = 0; c < 2; ++c) {
      int chunk = c * 4 + wid;
      gload_lds16(A + (size_t)(rowA + chunk * 16 + srow) * ld + k0 + scol, la + chunk * 512);
      gload_lds16(Bm + (size_t)(rowB + chunk * 16 + srow) * ld + k0 + scol, lb + chunk * 512);
    }
    asm volatile("s_waitcnt vmcnt(0)" ::: "memory");
    __syncthreads();
    bf16x8 af[4], bfr[4];
#pragma unroll
    for (int m = 0; m < 4; ++m)
      af[m] = *(const bf16x8*)(la + (wr * 64 + m * 16 + ar) * 32 + ak);
#pragma unroll
    for (int n = 0; n < 4; ++n)
      bfr[n] = *(const bf16x8*)(lb + (wc * 64 + n * 16 + ar) * 32 + ak);
#pragma unroll
    for (int m = 0; m < 4; ++m)
#pragma unroll
      for (int n = 0; n < 4; ++n)
        acc[m][n] = __builtin_amdgcn_mfma_f32_16x16x32_bf16(af[m], bfr[n], acc[m][n], 0, 0, 0);
    __syncthreads();
  }
}

// MODE 0: split-heads bf16 out [B,H,S,64]; MODE 1: V-transposed bf16 [B,H,64,S];
// MODE 2: plain fp32 out [M,N]
template <int MODE>
__global__ __launch_bounds__(256, 2) void gemm128(
    const short* __restrict__ A, const short* __restrict__ Bm,
    const float* __restrict__ bias, void* __restrict__ outp, int N, int ld, int nk) {
  __shared__ short la[128 * 32], lb[128 * 32];
  const int tid = threadIdx.x, wid = tid >> 6, lane = tid & 63;
  const int bM = blockIdx.y * 128, bN = blockIdx.x * 128;
  f32x4 acc[4][4];
#pragma unroll
  for (int m = 0; m < 4; ++m)
#pragma unroll
    for (int n = 0; n < 4; ++n) acc[m][n] = (f32x4){0.f, 0.f, 0.f, 0.f};
  gemm_core(A, Bm, bM, bN, ld, nk, la, lb, wid, lane, acc);
  const int wr = wid >> 1, wc = wid & 1;
#pragma unroll
  for (int m = 0; m < 4; ++m)
#pragma unroll
    for (int n = 0; n < 4; ++n)
#pragma unroll
      for (int r = 0; r < 4; ++r) {
        int gm = bM + wr * 64 + m * 16 + (lane >> 4) * 4 + r;
        int gn = bN + wc * 64 + n * 16 + (lane & 15);
        float val = acc[m][n][r] + bias[gn];
        if constexpr (MODE == 0) {
          int b = gm >> 11, s = gm & 2047, h = gn >> 6, d = gn & 63;
          ((short*)outp)[(((size_t)b * NH + h) * SS + s) * 64 + d] = f2bf(val);
        } else if constexpr (MODE == 1) {
          int b = gm >> 11, s = gm & 2047, h = gn >> 6, d = gn & 63;
          ((short*)outp)[(((size_t)b * NH + h) * 64 + d) * SS + s] = f2bf(val);
        } else {
          ((float*)outp)[(size_t)gm * N + gn] = val;
        }
      }
}

// ---------------- logits: per (b,h) qh[S,64] x kh[S,64]^T, scale+mask, fp32 out ----------------
__global__ __launch_bounds__(256, 2) void logits_k(
    const short* __restrict__ qh, const short* __restrict__ kh,
    const float* __restrict__ mask, float* __restrict__ wout) {
  __shared__ short la[128 * 32], lb[128 * 32];
  const int tid = threadIdx.x, wid = tid >> 6, lane = tid & 63;
  const int bh = blockIdx.z, b = bh >> 4;
  const short* A = qh + (size_t)bh * SS * 64;
  const short* Bm = kh + (size_t)bh * SS * 64;
  float* outp = wout + (size_t)bh * SS * SS;
  const int bM = blockIdx.y * 128, bN = blockIdx.x * 128;
  f32x4 acc[4][4];
#pragma unroll
  for (int m = 0; m < 4; ++m)
#pragma unroll
    for (int n = 0; n < 4; ++n) acc[m][n] = (f32x4){0.f, 0.f, 0.f, 0.f};
  gemm_core(A, Bm, bM, bN, 64, 2, la, lb, wid, lane, acc);
  const int wr = wid >> 1, wc = wid & 1;
#pragma unroll
  for (int m = 0; m < 4; ++m)
#pragma unroll
    for (int n = 0; n < 4; ++n) {
      int gn = bN + wc * 64 + n * 16 + (lane & 15);
      float mv = mask[b * SS + gn] * (-1e9f);
#pragma unroll
      for (int r = 0; r < 4; ++r) {
        int gm = bM + wr * 64 + m * 16 + (lane >> 4) * 4 + r;
        outp[(size_t)gm * SS + gn] = acc[m][n][r] * 0.125f + mv;
      }
    }
}

// ---------------- row softmax in-place: 1 wave per row of 2048 ----------------
__global__ __launch_bounds__(256) void softmax_k(float* __restrict__ w) {
  const size_t row = (size_t)blockIdx.x * 4 + (threadIdx.x >> 6);
  const int lane = threadIdx.x & 63;
  f32x4* p = (f32x4*)(w + row * SS);
  f32x4 v[8];
  float mx = -3.0e38f;
#pragma unroll
  for (int i = 0; i < 8; ++i) {
    v[i] = p[i * 64 + lane];
    mx = fmaxf(mx, fmaxf(fmaxf(v[i][0], v[i][1]), fmaxf(v[i][2], v[i][3])));
  }
#pragma unroll
  for (int o = 32; o >= 1; o >>= 1) mx = fmaxf(mx, __shfl_xor(mx, o, 64));
  float sum = 0.f;
#pragma unroll
  for (int i = 0; i < 8; ++i) {
#pragma unroll
    for (int j = 0; j < 4; ++j) {
      v[i][j] = __expf(v[i][j] - mx);
      sum += v[i][j];
    }
  }
#pragma unroll
  for (int o = 32; o >= 1; o >>= 1) sum += __shfl_xor(sum, o, 64);
  float inv = 1.f / sum;
#pragma unroll
  for (int i = 0; i < 8; ++i) {
    v[i][0] *= inv; v[i][1] *= inv; v[i][2] *= inv; v[i][3] *= inv;
    p[i * 64 + lane] = v[i];
  }
}

// ---------------- PV: per (b,h) weights[S,S] (fp32) x vhT[64,S]^T -> concat bf16 ----------------
__global__ __launch_bounds__(256, 2) void pv_k(
    const float* __restrict__ wts, const short* __restrict__ vhT,
    short* __restrict__ concat) {
  __shared__ short la[128 * 32], lb[64 * 32];
  const int tid = threadIdx.x, wid = tid >> 6, lane = tid & 63;
  const int bh = blockIdx.y, b = bh >> 4, h = bh & 15;
  const float* A = wts + (size_t)bh * SS * SS;
  const short* Bm = vhT + (size_t)bh * 64 * SS;
  const int bM = blockIdx.x * 128;
  f32x4 acc[2][4];
#pragma unroll
  for (int m = 0; m < 2; ++m)
#pragma unroll
    for (int n = 0; n < 4; ++n) acc[m][n] = (f32x4){0.f, 0.f, 0.f, 0.f};
  const int ar = lane & 15, ak = (lane >> 4) * 8;
  const int arow = tid >> 1, acol = (tid & 1) * 16;
  const int brow = wid * 16 + (lane >> 2), bcol = (lane & 3) * 8;
  for (int kt = 0; kt < SS / 32; ++kt) {
    const int k0 = kt * 32;
    // stage A (fp32 -> bf16 via regs)
    const f32x4* src = (const f32x4*)(A + (size_t)(bM + arow) * SS + k0 + acol);
    f32x4 x0 = src[0], x1 = src[1], x2 = src[2], x3 = src[3];
    bf16x8 o0, o1;
    o0[0] = f2bf(x0[0]); o0[1] = f2bf(x0[1]); o0[2] = f2bf(x0[2]); o0[3] = f2bf(x0[3]);
    o0[4] = f2bf(x1[0]); o0[5] = f2bf(x1[1]); o0[6] = f2bf(x1[2]); o0[7] = f2bf(x1[3]);
    o1[0] = f2bf(x2[0]); o1[1] = f2bf(x2[1]); o1[2] = f2bf(x2[2]); o1[3] = f2bf(x2[3]);
    o1[4] = f2bf(x3[0]); o1[5] = f2bf(x3[1]); o1[6] = f2bf(x3[2]); o1[7] = f2bf(x3[3]);
    short* dst = la + arow * 32 + acol;
    *(bf16x8*)dst = o0;
    *(bf16x8*)(dst + 8) = o1;
    // stage B (vhT rows = d) via global_load_lds
    gload_lds16(Bm + (size_t)brow * SS + k0 + bcol, lb + wid * 512);
    asm volatile("s_waitcnt vmcnt(0)" ::: "memory");
    __syncthreads();
    bf16x8 af[2], bfr[4];
#pragma unroll
    for (int m = 0; m < 2; ++m)
      af[m] = *(const bf16x8*)(la + (wid * 32 + m * 16 + ar) * 32 + ak);
#pragma unroll
    for (int n = 0; n < 4; ++n)
      bfr[n] = *(const bf16x8*)(lb + (n * 16 + ar) * 32 + ak);
#pragma unroll
    for (int m = 0; m < 2; ++m)
#pragma unroll
      for (int n = 0; n < 4; ++n)
        acc[m][n] = __builtin_amdgcn_mfma_f32_16x16x32_bf16(af[m], bfr[n], acc[m][n], 0, 0, 0);
    __syncthreads();
  }
#pragma unroll
  for (int m = 0; m < 2; ++m)
#pragma unroll
    for (int n = 0; n < 4; ++n)
#pragma unroll
      for (int r = 0; r < 4; ++r) {
        int s = bM + wid * 32 + m * 16 + (lane >> 4) * 4 + r;
        int d = n * 16 + (lane & 15);
        concat[((size_t)(b * SS + s)) * DDim + h * 64 + d] = f2bf(acc[m][n][r]);
      }
}

extern "C" void kernel_launch(void* const* d_in, const int* in_sizes, int n_in,
                              void* d_out, int out_size, void* d_ws, size_t ws_size,
                              hipStream_t stream) {
  const float* q = (const float*)d_in[0];
  const float* k = (const float*)d_in[1];
  const float* v = (const float*)d_in[2];
  const float* mask = (const float*)d_in[3];
  const float* wq_w = (const float*)d_in[4];
  const float* wq_b = (const float*)d_in[5];
  const float* wk_w = (const float*)d_in[6];
  const float* wk_b = (const float*)d_in[7];
  const float* wv_w = (const float*)d_in[8];
  const float* wv_b = (const float*)d_in[9];
  const float* wo_w = (const float*)d_in[10];
  const float* wo_b = (const float*)d_in[11];

  // ws layout (shorts)
  short* qb = (short*)d_ws;
  short* kb = qb + BSD;
  short* vb = kb + BSD;
  short* wqb = vb + BSD;
  short* wkb = wqb + DDn;
  short* wvb = wkb + DDn;
  short* wob = wvb + DDn;
  short* qh = wob + DDn;
  short* kh = qh + BSD;
  short* vhT = kh + BSD;
  short* concat = vhT + BSD;

  float* out0 = (float*)d_out;
  float* wts = out0 + BSD;  // [B,H,S,S] fp32

  const int n8_bsd = (int)(BSD / 8), n8_dd = (int)(DDn / 8);
  cvt_k<<<n8_bsd / 256, 256, 0, stream>>>(q, qb, n8_bsd);
  cvt_k<<<n8_bsd / 256, 256, 0, stream>>>(k, kb, n8_bsd);
  cvt_k<<<n8_bsd / 256, 256, 0, stream>>>(v, vb, n8_bsd);
  cvt_k<<<n8_dd / 256, 256, 0, stream>>>(wq_w, wqb, n8_dd);
  cvt_k<<<n8_dd / 256, 256, 0, stream>>>(wk_w, wkb, n8_dd);
  cvt_k<<<n8_dd / 256, 256, 0, stream>>>(wv_w, wvb, n8_dd);
  cvt_k<<<n8_dd / 256, 256, 0, stream>>>(wo_w, wob, n8_dd);

  dim3 gproj(DDim / 128, (NB * SS) / 128);  // (8, 32)
  gemm128<0><<<gproj, 256, 0, stream>>>(qb, wqb, wq_b, qh, DDim, DDim, DDim / 32);
  gemm128<0><<<gproj, 256, 0, stream>>>(kb, wkb, wk_b, kh, DDim, DDim, DDim / 32);
  gemm128<1><<<gproj, 256, 0, stream>>>(vb, wvb, wv_b, vhT, DDim, DDim, DDim / 32);

  dim3 glog(SS / 128, SS / 128, NB * NH);  // (16,16,32)
  logits_k<<<glog, 256, 0, stream>>>(qh, kh, mask, wts);

  softmax_k<<<(NB * NH * SS) / 4, 256, 0, stream>>>(wts);

  dim3 gpv(SS / 128, NB * NH);  // (16, 32)
  pv_k<<<gpv, 256, 0, stream>>>(wts, vhT, concat);

  gemm128<2><<<gproj, 256, 0, stream>>>(concat, wob, wo_b, (void*)out0, DDim, DDim, DDim / 32);
}

// Round 2
// 331.362 us; speedup vs baseline: 1.9024x; 1.9024x over previous
//
#include <hip/hip_runtime.h>
#include <stdint.h>
#include <stddef.h>

static constexpr int NB = 2;       // batch
static constexpr int SS = 2048;    // seq
static constexpr int DDim = 1024;  // model dim
static constexpr int NH = 16;      // heads
static constexpr size_t BSD = (size_t)NB * SS * DDim;  // 4194304
static constexpr size_t DDn = (size_t)DDim * DDim;     // 1048576

typedef __attribute__((ext_vector_type(4))) float f32x4;
typedef __attribute__((ext_vector_type(8))) short bf16x8;

__device__ __forceinline__ short f2bf(float f) {
  union { float f; unsigned u; } v; v.f = f;
  unsigned r = v.u + 0x7FFFu + ((v.u >> 16) & 1u);
  return (short)(r >> 16);
}

__device__ __forceinline__ void gload_lds16(const void* src, void* dst) {
  __builtin_amdgcn_global_load_lds(
      (const __attribute__((address_space(1))) void*)src,
      (__attribute__((address_space(3))) void*)dst, 16, 0, 0);
}

// ---------------- fp32 -> bf16 convert (8 elems/thread) ----------------
__global__ void cvt_k(const float* __restrict__ in, short* __restrict__ out, int n8) {
  int i = blockIdx.x * 256 + threadIdx.x;
  if (i >= n8) return;
  const f32x4* p = (const f32x4*)in + (size_t)i * 2;
  f32x4 a = p[0], c = p[1];
  bf16x8 o;
  o[0] = f2bf(a[0]); o[1] = f2bf(a[1]); o[2] = f2bf(a[2]); o[3] = f2bf(a[3]);
  o[4] = f2bf(c[0]); o[5] = f2bf(c[1]); o[6] = f2bf(c[2]); o[7] = f2bf(c[3]);
  ((bf16x8*)out)[i] = o;
}

// ---------------- shared 128x128 bf16 C=A*B^T core (projections) ----------------
__device__ __forceinline__ void gemm_core(
    const short* __restrict__ A, const short* __restrict__ Bm,
    int rowA, int rowB, int ld, int nk,
    short* la, short* lb, int wid, int lane, f32x4 (&acc)[4][4]) {
  const int ar = lane & 15, ak = (lane >> 4) * 8;
  const int srow = lane >> 2, scol = (lane & 3) * 8;
  const int wr = wid >> 1, wc = wid & 1;
  for (int kt = 0; kt < nk; ++kt) {
    const int k0 = kt * 32;
#pragma unroll
    for (int c = 0; c < 2; ++c) {
      int chunk = c * 4 + wid;
      gload_lds16(A + (size_t)(rowA + chunk * 16 + srow) * ld + k0 + scol, la + chunk * 512);
      gload_lds16(Bm + (size_t)(rowB + chunk * 16 + srow) * ld + k0 + scol, lb + chunk * 512);
    }
    asm volatile("s_waitcnt vmcnt(0)" ::: "memory");
    __syncthreads();
    bf16x8 af[4], bfr[4];
#pragma unroll
    for (int m = 0; m < 4; ++m)
      af[m] = *(const bf16x8*)(la + (wr * 64 + m * 16 + ar) * 32 + ak);
#pragma unroll
    for (int n = 0; n < 4; ++n)
      bfr[n] = *(const bf16x8*)(lb + (wc * 64 + n * 16 + ar) * 32 + ak);
#pragma unroll
    for (int m = 0; m < 4; ++m)
#pragma unroll
      for (int n = 0; n < 4; ++n)
        acc[m][n] = __builtin_amdgcn_mfma_f32_16x16x32_bf16(af[m], bfr[n], acc[m][n], 0, 0, 0);
    __syncthreads();
  }
}

// MODE 0: split-heads bf16 [B,H,S,64]; MODE 1: V^T bf16 [B,H,64,S]; MODE 2: fp32 [M,N]
template <int MODE>
__global__ __launch_bounds__(256, 2) void gemm128(
    const short* __restrict__ A, const short* __restrict__ Bm,
    const float* __restrict__ bias, void* __restrict__ outp, int N, int ld, int nk) {
  __shared__ short la[128 * 32], lb[128 * 32];
  const int tid = threadIdx.x, wid = tid >> 6, lane = tid & 63;
  const int bM = blockIdx.y * 128, bN = blockIdx.x * 128;
  f32x4 acc[4][4];
#pragma unroll
  for (int m = 0; m < 4; ++m)
#pragma unroll
    for (int n = 0; n < 4; ++n) acc[m][n] = (f32x4){0.f, 0.f, 0.f, 0.f};
  gemm_core(A, Bm, bM, bN, ld, nk, la, lb, wid, lane, acc);
  const int wr = wid >> 1, wc = wid & 1;
#pragma unroll
  for (int m = 0; m < 4; ++m)
#pragma unroll
    for (int n = 0; n < 4; ++n)
#pragma unroll
      for (int r = 0; r < 4; ++r) {
        int gm = bM + wr * 64 + m * 16 + (lane >> 4) * 4 + r;
        int gn = bN + wc * 64 + n * 16 + (lane & 15);
        float val = acc[m][n][r] + bias[gn];
        if constexpr (MODE == 0) {
          int b = gm >> 11, s = gm & 2047, h = gn >> 6, d = gn & 63;
          ((short*)outp)[(((size_t)b * NH + h) * SS + s) * 64 + d] = f2bf(val);
        } else if constexpr (MODE == 1) {
          int b = gm >> 11, s = gm & 2047, h = gn >> 6, d = gn & 63;
          ((short*)outp)[(((size_t)b * NH + h) * 64 + d) * SS + s] = f2bf(val);
        } else {
          ((float*)outp)[(size_t)gm * N + gn] = val;
        }
      }
}

// ---------------- fused attention: logits + softmax + weights-write + PV ----------------
// One block = one (b,h), one 128-row q-tile. Two sweeps over K; QK^T recomputed in
// sweep 2 to avoid re-reading the 537MB score matrix. All LDS tiles XOR-swizzled
// (byte_in_row ^= (row&7)<<4) via pre-swizzled global_load_lds sources.
__global__ __launch_bounds__(256, 2) void attn_k(
    const short* __restrict__ qh, const short* __restrict__ kh,
    const short* __restrict__ vhT, const float* __restrict__ mask,
    float* __restrict__ wout, short* __restrict__ concat) {
  __shared__ short lP[128 * 128];  // Q staging, then P tile (bf16, swizzled)
  __shared__ short lK[128 * 64];   // K tile (swizzled)
  __shared__ short lV[64 * 128];   // V^T tile (swizzled)
  __shared__ float lmask[2048];
  __shared__ float lrs[2][128];
  const int tid = threadIdx.x, wid = tid >> 6, lane = tid & 63;
  const int wr = wid >> 1, wc = wid & 1;
  const int bh = blockIdx.y, b = bh >> 4, h = bh & 15;
  const int bM = blockIdx.x * 128;
  const short* Qb = qh + (size_t)bh * SS * 64 + (size_t)bM * 64;
  const short* Kb = kh + (size_t)bh * SS * 64;
  const short* Vb = vhT + (size_t)bh * 64 * SS;
  float* Wb = wout + (size_t)bh * SS * SS;

#pragma unroll
  for (int i = 0; i < 8; ++i)
    lmask[tid + i * 256] = mask[b * SS + tid + i * 256] * (-1e9f);

  // stage Q tile [128][64] (contiguous) swizzled into lP
#pragma unroll
  for (int c = 0; c < 4; ++c) {
    int ob = c * 4096 + tid * 16;
    int row = ob >> 7, inrow = ob & 127;
    gload_lds16(Qb + row * 64 + ((inrow ^ ((row & 7) << 4)) >> 1), (char*)lP + ob);
  }
  asm volatile("s_waitcnt vmcnt(0)" ::: "memory");
  __syncthreads();
  bf16x8 af[4][2];
#pragma unroll
  for (int m = 0; m < 4; ++m)
#pragma unroll
    for (int kk = 0; kk < 2; ++kk) {
      int row = wr * 64 + m * 16 + (lane & 15);
      int kb = (kk * 32 + (lane >> 4) * 8) * 2;
      af[m][kk] = *(const bf16x8*)((const char*)lP + row * 128 + (kb ^ ((row & 7) << 4)));
    }

  // ---- sweep 1: row sums of exp(logit + mask) ----
  float ps[4][4];
#pragma unroll
  for (int m = 0; m < 4; ++m)
#pragma unroll
    for (int r = 0; r < 4; ++r) ps[m][r] = 0.f;

  for (int kt = 0; kt < 16; ++kt) {
    __syncthreads();
#pragma unroll
    for (int c = 0; c < 4; ++c) {
      int ob = c * 4096 + tid * 16;
      int row = ob >> 7, inrow = ob & 127;
      gload_lds16(Kb + (size_t)(kt * 128 + row) * 64 + ((inrow ^ ((row & 7) << 4)) >> 1),
                  (char*)lK + ob);
    }
    asm volatile("s_waitcnt vmcnt(0)" ::: "memory");
    __syncthreads();
    bf16x8 bfr[4][2];
#pragma unroll
    for (int n = 0; n < 4; ++n)
#pragma unroll
      for (int kk = 0; kk < 2; ++kk) {
        int row = wc * 64 + n * 16 + (lane & 15);
        int kb = (kk * 32 + (lane >> 4) * 8) * 2;
        bfr[n][kk] = *(const bf16x8*)((const char*)lK + row * 128 + (kb ^ ((row & 7) << 4)));
      }
#pragma unroll
    for (int n = 0; n < 4; ++n) {
      float mv = lmask[kt * 128 + wc * 64 + n * 16 + (lane & 15)];
#pragma unroll
      for (int m = 0; m < 4; ++m) {
        f32x4 a = (f32x4){0.f, 0.f, 0.f, 0.f};
        a = __builtin_amdgcn_mfma_f32_16x16x32_bf16(af[m][0], bfr[n][0], a, 0, 0, 0);
        a = __builtin_amdgcn_mfma_f32_16x16x32_bf16(af[m][1], bfr[n][1], a, 0, 0, 0);
#pragma unroll
        for (int r = 0; r < 4; ++r) ps[m][r] += __expf(a[r] * 0.125f + mv);
      }
    }
  }
  // reduce over the 16 lanes holding one row's 16 cols
#pragma unroll
  for (int m = 0; m < 4; ++m)
#pragma unroll
    for (int r = 0; r < 4; ++r) {
      float s = ps[m][r];
      s += __shfl_xor(s, 1, 64);
      s += __shfl_xor(s, 2, 64);
      s += __shfl_xor(s, 4, 64);
      s += __shfl_xor(s, 8, 64);
      ps[m][r] = s;
    }
  if ((lane & 15) == 0) {
#pragma unroll
    for (int m = 0; m < 4; ++m)
#pragma unroll
      for (int r = 0; r < 4; ++r)
        lrs[wc][wr * 64 + m * 16 + (lane >> 4) * 4 + r] = ps[m][r];
  }
  __syncthreads();
  float inv[4][4];
#pragma unroll
  for (int m = 0; m < 4; ++m)
#pragma unroll
    for (int r = 0; r < 4; ++r) {
      int row = wr * 64 + m * 16 + (lane >> 4) * 4 + r;
      inv[m][r] = 1.f / (lrs[0][row] + lrs[1][row]);
    }

  // ---- sweep 2: recompute logits, write weights, PV accumulate ----
  f32x4 pacc[4][2];
#pragma unroll
  for (int m = 0; m < 4; ++m)
#pragma unroll
    for (int n = 0; n < 2; ++n) pacc[m][n] = (f32x4){0.f, 0.f, 0.f, 0.f};

  for (int kt = 0; kt < 16; ++kt) {
    __syncthreads();
#pragma unroll
    for (int c = 0; c < 4; ++c) {
      int ob = c * 4096 + tid * 16;
      int row = ob >> 7, inrow = ob & 127;
      gload_lds16(Kb + (size_t)(kt * 128 + row) * 64 + ((inrow ^ ((row & 7) << 4)) >> 1),
                  (char*)lK + ob);
    }
#pragma unroll
    for (int c = 0; c < 4; ++c) {
      int ob = c * 4096 + tid * 16;
      int row = ob >> 8, inrow = ob & 255;
      gload_lds16(Vb + (size_t)row * SS + kt * 128 + ((inrow ^ ((row & 7) << 4)) >> 1),
                  (char*)lV + ob);
    }
    asm volatile("s_waitcnt vmcnt(0)" ::: "memory");
    __syncthreads();
    bf16x8 bfr[4][2];
#pragma unroll
    for (int n = 0; n < 4; ++n)
#pragma unroll
      for (int kk = 0; kk < 2; ++kk) {
        int row = wc * 64 + n * 16 + (lane & 15);
        int kb = (kk * 32 + (lane >> 4) * 8) * 2;
        bfr[n][kk] = *(const bf16x8*)((const char*)lK + row * 128 + (kb ^ ((row & 7) << 4)));
      }
#pragma unroll
    for (int n = 0; n < 4; ++n) {
      int col = wc * 64 + n * 16 + (lane & 15);
      float mv = lmask[kt * 128 + col];
#pragma unroll
      for (int m = 0; m < 4; ++m) {
        f32x4 a = (f32x4){0.f, 0.f, 0.f, 0.f};
        a = __builtin_amdgcn_mfma_f32_16x16x32_bf16(af[m][0], bfr[n][0], a, 0, 0, 0);
        a = __builtin_amdgcn_mfma_f32_16x16x32_bf16(af[m][1], bfr[n][1], a, 0, 0, 0);
#pragma unroll
        for (int r = 0; r < 4; ++r) {
          int prow = wr * 64 + m * 16 + (lane >> 4) * 4 + r;
          float w = __expf(a[r] * 0.125f + mv) * inv[m][r];
          Wb[(size_t)(bM + prow) * SS + kt * 128 + col] = w;
          *(short*)((char*)lP + prow * 256 + ((col * 2) ^ ((prow & 7) << 4))) = f2bf(w);
        }
      }
    }
    __syncthreads();
    // PV: out[q][d] += P[q][k] * V^T[d][k]
#pragma unroll
    for (int kk = 0; kk < 4; ++kk) {
      bf16x8 pa[4], bv[2];
      int kb = (kk * 32 + (lane >> 4) * 8) * 2;
#pragma unroll
      for (int m = 0; m < 4; ++m) {
        int row = wr * 64 + m * 16 + (lane & 15);
        pa[m] = *(const bf16x8*)((const char*)lP + row * 256 + (kb ^ ((row & 7) << 4)));
      }
#pragma unroll
      for (int n = 0; n < 2; ++n) {
        int d = wc * 32 + n * 16 + (lane & 15);
        bv[n] = *(const bf16x8*)((const char*)lV + d * 256 + (kb ^ ((d & 7) << 4)));
      }
#pragma unroll
      for (int m = 0; m < 4; ++m)
#pragma unroll
        for (int n = 0; n < 2; ++n)
          pacc[m][n] = __builtin_amdgcn_mfma_f32_16x16x32_bf16(pa[m], bv[n], pacc[m][n], 0, 0, 0);
    }
  }
  // epilogue: attn (concat layout) bf16
#pragma unroll
  for (int m = 0; m < 4; ++m)
#pragma unroll
    for (int n = 0; n < 2; ++n)
#pragma unroll
      for (int r = 0; r < 4; ++r) {
        int s = bM + wr * 64 + m * 16 + (lane >> 4) * 4 + r;
        int d = wc * 32 + n * 16 + (lane & 15);
        concat[((size_t)(b * SS + s)) * DDim + h * 64 + d] = f2bf(pacc[m][n][r]);
      }
}

extern "C" void kernel_launch(void* const* d_in, const int* in_sizes, int n_in,
                              void* d_out, int out_size, void* d_ws, size_t ws_size,
                              hipStream_t stream) {
  const float* q = (const float*)d_in[0];
  const float* k = (const float*)d_in[1];
  const float* v = (const float*)d_in[2];
  const float* mask = (const float*)d_in[3];
  const float* wq_w = (const float*)d_in[4];
  const float* wq_b = (const float*)d_in[5];
  const float* wk_w = (const float*)d_in[6];
  const float* wk_b = (const float*)d_in[7];
  const float* wv_w = (const float*)d_in[8];
  const float* wv_b = (const float*)d_in[9];
  const float* wo_w = (const float*)d_in[10];
  const float* wo_b = (const float*)d_in[11];

  short* qb = (short*)d_ws;
  short* kb = qb + BSD;
  short* vb = kb + BSD;
  short* wqb = vb + BSD;
  short* wkb = wqb + DDn;
  short* wvb = wkb + DDn;
  short* wob = wvb + DDn;
  short* qh = wob + DDn;
  short* kh = qh + BSD;
  short* vhT = kh + BSD;
  short* concat = vhT + BSD;

  float* out0 = (float*)d_out;
  float* wts = out0 + BSD;  // [B,H,S,S] fp32

  const int n8_bsd = (int)(BSD / 8), n8_dd = (int)(DDn / 8);
  cvt_k<<<n8_bsd / 256, 256, 0, stream>>>(q, qb, n8_bsd);
  cvt_k<<<n8_bsd / 256, 256, 0, stream>>>(k, kb, n8_bsd);
  cvt_k<<<n8_bsd / 256, 256, 0, stream>>>(v, vb, n8_bsd);
  cvt_k<<<n8_dd / 256, 256, 0, stream>>>(wq_w, wqb, n8_dd);
  cvt_k<<<n8_dd / 256, 256, 0, stream>>>(wk_w, wkb, n8_dd);
  cvt_k<<<n8_dd / 256, 256, 0, stream>>>(wv_w, wvb, n8_dd);
  cvt_k<<<n8_dd / 256, 256, 0, stream>>>(wo_w, wob, n8_dd);

  dim3 gproj(DDim / 128, (NB * SS) / 128);  // (8, 32)
  gemm128<0><<<gproj, 256, 0, stream>>>(qb, wqb, wq_b, qh, DDim, DDim, DDim / 32);
  gemm128<0><<<gproj, 256, 0, stream>>>(kb, wkb, wk_b, kh, DDim, DDim, DDim / 32);
  gemm128<1><<<gproj, 256, 0, stream>>>(vb, wvb, wv_b, vhT, DDim, DDim, DDim / 32);

  dim3 gattn(SS / 128, NB * NH);  // (16, 32)
  attn_k<<<gattn, 256, 0, stream>>>(qh, kh, vhT, mask, wts, concat);

  gemm128<2><<<gproj, 256, 0, stream>>>(concat, wob, wo_b, (void*)out0, DDim, DDim, DDim / 32);
}